// Round 1
// baseline (3113.500 us; speedup 1.0000x reference)
//
#include <hip/hip_runtime.h>
#include <hip/hip_bf16.h>

// Problem constants (from reference): B=2, T=2048, D=2048, H=16, HKV=4, HD=128
#define B_    2
#define T_    2048
#define D_    2048
#define H_    16
#define HKV_  4
#define HD_   128
#define G_    (H_ / HKV_)          // 4 query heads per kv head
#define BT_   (B_ * T_)            // 4096 rows
#define QD_   (H_ * HD_)           // 2048
#define KVD_  (HKV_ * HD_)         // 512

// ---------------------------------------------------------------------------
// SGEMM: C[M,N] = A[M,K] @ B[K,N], all row-major fp32.
// M,N,K must be multiples of 64/64/16 (true for all four projections here).
// 64x64 block tile, BK=16, 256 threads, each thread computes a 4x4 microtile.
// ---------------------------------------------------------------------------
#define BM 64
#define BN 64
#define BK 16

__global__ __launch_bounds__(256)
void sgemm_kernel(const float* __restrict__ A,
                  const float* __restrict__ Bm,
                  float* __restrict__ C,
                  int M, int N, int K) {
    __shared__ float As[BK][BM];   // transposed: As[k][m]
    __shared__ float Bs[BK][BN];   // natural:    Bs[k][n]

    const int tid  = threadIdx.x;
    const int tx   = tid & 15;     // 0..15 : column group
    const int ty   = tid >> 4;     // 0..15 : row group
    const int brow = blockIdx.y * BM;
    const int bcol = blockIdx.x * BN;

    // A tile load mapping: 64 rows x 16 cols = 256 float4 (one per thread)
    const int arow  = tid >> 2;           // 0..63
    const int ak4   = (tid & 3) * 4;      // 0,4,8,12
    // B tile load mapping: 16 rows x 64 cols = 256 float4 (one per thread)
    const int bkrow = tid >> 4;           // 0..15
    const int bn4   = (tid & 15) * 4;     // 0..60

    float acc[4][4] = {};

    for (int k0 = 0; k0 < K; k0 += BK) {
        float4 av = *reinterpret_cast<const float4*>(
            &A[(size_t)(brow + arow) * K + (k0 + ak4)]);
        As[ak4 + 0][arow] = av.x;
        As[ak4 + 1][arow] = av.y;
        As[ak4 + 2][arow] = av.z;
        As[ak4 + 3][arow] = av.w;

        *reinterpret_cast<float4*>(&Bs[bkrow][bn4]) =
            *reinterpret_cast<const float4*>(
                &Bm[(size_t)(k0 + bkrow) * N + (bcol + bn4)]);

        __syncthreads();

#pragma unroll
        for (int kk = 0; kk < BK; ++kk) {
            float4 a = *reinterpret_cast<const float4*>(&As[kk][ty * 4]);
            float4 b = *reinterpret_cast<const float4*>(&Bs[kk][tx * 4]);
            float ar[4] = {a.x, a.y, a.z, a.w};
            float br[4] = {b.x, b.y, b.z, b.w};
#pragma unroll
            for (int i = 0; i < 4; ++i)
#pragma unroll
                for (int j = 0; j < 4; ++j)
                    acc[i][j] = fmaf(ar[i], br[j], acc[i][j]);
        }
        __syncthreads();
    }

#pragma unroll
    for (int i = 0; i < 4; ++i) {
        float4 o = make_float4(acc[i][0], acc[i][1], acc[i][2], acc[i][3]);
        *reinterpret_cast<float4*>(
            &C[(size_t)(brow + ty * 4 + i) * N + (bcol + tx * 4)]) = o;
    }
}

// ---------------------------------------------------------------------------
// RoPE (in-place). x: [BT_][NH*128]. Pair (d, d+64) within each head rotated
// by angle t * theta^(-d/64), t = row % T_.
// ---------------------------------------------------------------------------
__global__ void rope_kernel(float* __restrict__ x, int NH) {
    const int total = BT_ * NH * 64;
    const float neg_ln_theta_over_64 = -0.14391156642478335f; // -ln(10000)/64
    for (int idx = blockIdx.x * blockDim.x + threadIdx.x; idx < total;
         idx += gridDim.x * blockDim.x) {
        const int i   = idx & 63;                 // freq index 0..63
        const int h   = (idx >> 6) % NH;
        const int row = idx / (NH * 64);          // 0..BT_-1
        const int t   = row % T_;

        const float inv = __expf((float)i * neg_ln_theta_over_64);
        const float ang = (float)t * inv;
        float s, c;
        sincosf(ang, &s, &c);

        const size_t base = (size_t)row * (NH * 128) + (size_t)h * 128 + i;
        const float x1 = x[base];
        const float x2 = x[base + 64];
        x[base]      = x1 * c - x2 * s;
        x[base + 64] = x2 * c + x1 * s;
    }
}

// ---------------------------------------------------------------------------
// Flash-style GQA attention (fp32).
// Block = (b, h, q-tile of 32 rows). 256 threads.
// Phase 1: 16x16 threads compute a 32x32 score tile (2x2 each) from LDS.
// Phase 2: 8 threads per query row do online softmax + PV over a 16-wide
//          d-slice each.
// Output written as (b, t, h, d) contiguous — may alias the q buffer
// (each block reads its own q region into LDS before writing it).
// ---------------------------------------------------------------------------
#define QT 32
#define KT 32
#define LDP 132   // padded row stride (floats): keeps 16B alignment, shifts banks

__global__ __launch_bounds__(256)
void attn_kernel(const float* __restrict__ q,
                 const float* __restrict__ k,
                 const float* __restrict__ v,
                 const int*   __restrict__ amask,
                 const int*   __restrict__ causal_p,
                 float* __restrict__ out) {
    __shared__ float Qs[QT][LDP];
    __shared__ float Ks[KT][LDP];
    __shared__ float Vs[KT][LDP];
    __shared__ float Ss[QT][KT + 1];

    const int nq  = T_ / QT;
    const int bh  = blockIdx.x / nq;
    const int q0  = (blockIdx.x % nq) * QT;
    const int b   = bh / H_;
    const int h   = bh % H_;
    const int kv  = h / G_;
    const int causal = *causal_p;
    const int tid = threadIdx.x;

    // load Q tile: 32x128 = 1024 float4 / 256 threads = 4 each
    for (int i = tid; i < QT * (HD_ / 4); i += 256) {
        const int r  = i / (HD_ / 4);
        const int c4 = (i % (HD_ / 4)) * 4;
        *reinterpret_cast<float4*>(&Qs[r][c4]) =
            *reinterpret_cast<const float4*>(
                &q[(size_t)(b * T_ + q0 + r) * QD_ + h * HD_ + c4]);
    }

    const int ty = tid >> 4, tx = tid & 15;     // score phase mapping
    const int srow = tid >> 3, ssub = tid & 7;  // softmax/PV mapping

    float m_run = -__builtin_inff();
    float l_run = 0.0f;
    float acc[16] = {};

    const int smax = causal ? (q0 + QT) : T_;
    __syncthreads();

    for (int s0 = 0; s0 < smax; s0 += KT) {
        // load K,V tiles (32x128 each)
        for (int i = tid; i < KT * (HD_ / 4); i += 256) {
            const int r  = i / (HD_ / 4);
            const int c4 = (i % (HD_ / 4)) * 4;
            const size_t gbase =
                (size_t)(b * T_ + s0 + r) * KVD_ + kv * HD_ + c4;
            *reinterpret_cast<float4*>(&Ks[r][c4]) =
                *reinterpret_cast<const float4*>(&k[gbase]);
            *reinterpret_cast<float4*>(&Vs[r][c4]) =
                *reinterpret_cast<const float4*>(&v[gbase]);
        }
        __syncthreads();

        // ---- scores: thread (ty,tx) computes S[2ty+i][2tx+j] ----
        float sc00 = 0.f, sc01 = 0.f, sc10 = 0.f, sc11 = 0.f;
#pragma unroll 8
        for (int d4 = 0; d4 < HD_; d4 += 4) {
            const float4 qa = *reinterpret_cast<const float4*>(&Qs[ty * 2 + 0][d4]);
            const float4 qb = *reinterpret_cast<const float4*>(&Qs[ty * 2 + 1][d4]);
            const float4 ka = *reinterpret_cast<const float4*>(&Ks[tx * 2 + 0][d4]);
            const float4 kb = *reinterpret_cast<const float4*>(&Ks[tx * 2 + 1][d4]);
            sc00 = fmaf(qa.x, ka.x, fmaf(qa.y, ka.y, fmaf(qa.z, ka.z, fmaf(qa.w, ka.w, sc00))));
            sc01 = fmaf(qa.x, kb.x, fmaf(qa.y, kb.y, fmaf(qa.z, kb.z, fmaf(qa.w, kb.w, sc01))));
            sc10 = fmaf(qb.x, ka.x, fmaf(qb.y, ka.y, fmaf(qb.z, ka.z, fmaf(qb.w, ka.w, sc10))));
            sc11 = fmaf(qb.x, kb.x, fmaf(qb.y, kb.y, fmaf(qb.z, kb.z, fmaf(qb.w, kb.w, sc11))));
        }
        const float rscale = 0.08838834764831845f;  // 1/sqrt(128)
        {
            const float scv[2][2] = {{sc00, sc01}, {sc10, sc11}};
#pragma unroll
            for (int i = 0; i < 2; ++i) {
#pragma unroll
                for (int j = 0; j < 2; ++j) {
                    const int tq = q0 + ty * 2 + i;
                    const int sk = s0 + tx * 2 + j;
                    float val = scv[i][j] * rscale;
                    if ((causal && sk > tq) || amask[b * T_ + sk] == 0)
                        val = -__builtin_inff();
                    Ss[ty * 2 + i][tx * 2 + j] = val;
                }
            }
        }
        __syncthreads();

        // ---- online softmax + PV: row srow, d-slice [ssub*16, ssub*16+16) ----
        float tmax = -__builtin_inff();
#pragma unroll
        for (int s = 0; s < KT; ++s) tmax = fmaxf(tmax, Ss[srow][s]);
        const float m_new = fmaxf(m_run, tmax);
        if (m_new != -__builtin_inff()) {
            const float corr = __expf(m_run - m_new);  // exp(-inf)=0 on first tile
            l_run *= corr;
#pragma unroll
            for (int d = 0; d < 16; ++d) acc[d] *= corr;
            float psum = 0.f;
            for (int s = 0; s < KT; ++s) {
                const float p = __expf(Ss[srow][s] - m_new);
                psum += p;
                const float* vrow = &Vs[s][ssub * 16];
                const float4 v0 = *reinterpret_cast<const float4*>(vrow + 0);
                const float4 v1 = *reinterpret_cast<const float4*>(vrow + 4);
                const float4 v2 = *reinterpret_cast<const float4*>(vrow + 8);
                const float4 v3 = *reinterpret_cast<const float4*>(vrow + 12);
                acc[0]  = fmaf(p, v0.x, acc[0]);  acc[1]  = fmaf(p, v0.y, acc[1]);
                acc[2]  = fmaf(p, v0.z, acc[2]);  acc[3]  = fmaf(p, v0.w, acc[3]);
                acc[4]  = fmaf(p, v1.x, acc[4]);  acc[5]  = fmaf(p, v1.y, acc[5]);
                acc[6]  = fmaf(p, v1.z, acc[6]);  acc[7]  = fmaf(p, v1.w, acc[7]);
                acc[8]  = fmaf(p, v2.x, acc[8]);  acc[9]  = fmaf(p, v2.y, acc[9]);
                acc[10] = fmaf(p, v2.z, acc[10]); acc[11] = fmaf(p, v2.w, acc[11]);
                acc[12] = fmaf(p, v3.x, acc[12]); acc[13] = fmaf(p, v3.y, acc[13]);
                acc[14] = fmaf(p, v3.z, acc[14]); acc[15] = fmaf(p, v3.w, acc[15]);
            }
            l_run += psum;
            m_run = m_new;
        }
        __syncthreads();
    }

    // ---- write output: (b, t, h, d) contiguous; may alias q ----
    const float invl = (l_run > 0.f) ? (1.0f / l_run) : 0.f;
    const size_t obase =
        (size_t)(b * T_ + q0 + srow) * QD_ + h * HD_ + ssub * 16;
#pragma unroll
    for (int dd = 0; dd < 16; dd += 4) {
        float4 o = make_float4(acc[dd] * invl, acc[dd + 1] * invl,
                               acc[dd + 2] * invl, acc[dd + 3] * invl);
        *reinterpret_cast<float4*>(&out[obase + dd]) = o;
    }
}

// ---------------------------------------------------------------------------
// kernel_launch
// d_in: 0=x f32[B,T,D], 1=attention_mask i32[B,T], 2=causal i32[1],
//       3=wq f32[D,2048], 4=wk f32[D,512], 5=wv f32[D,512], 6=wo f32[D,D]
// d_out: f32[B,T,D]
// workspace: qbuf (BT x 2048) | kbuf (BT x 512) | vbuf (BT x 512) = ~50.3 MB
// ---------------------------------------------------------------------------
extern "C" void kernel_launch(void* const* d_in, const int* in_sizes, int n_in,
                              void* d_out, int out_size, void* d_ws, size_t ws_size,
                              hipStream_t stream) {
    const float* x      = (const float*)d_in[0];
    const int*   amask  = (const int*)d_in[1];
    const int*   causal = (const int*)d_in[2];
    const float* wq     = (const float*)d_in[3];
    const float* wk     = (const float*)d_in[4];
    const float* wv     = (const float*)d_in[5];
    const float* wo     = (const float*)d_in[6];
    float* out = (float*)d_out;

    float* qbuf = (float*)d_ws;                          // BT_ * QD_
    float* kbuf = qbuf + (size_t)BT_ * QD_;              // BT_ * KVD_
    float* vbuf = kbuf + (size_t)BT_ * KVD_;             // BT_ * KVD_

    const dim3 blk(256);

    // QKV projections
    sgemm_kernel<<<dim3(QD_ / BN, BT_ / BM), blk, 0, stream>>>(x, wq, qbuf, BT_, QD_, D_);
    sgemm_kernel<<<dim3(KVD_ / BN, BT_ / BM), blk, 0, stream>>>(x, wk, kbuf, BT_, KVD_, D_);
    sgemm_kernel<<<dim3(KVD_ / BN, BT_ / BM), blk, 0, stream>>>(x, wv, vbuf, BT_, KVD_, D_);

    // RoPE on q and k (in-place)
    rope_kernel<<<dim3(2048), blk, 0, stream>>>(qbuf, H_);
    rope_kernel<<<dim3(512), blk, 0, stream>>>(kbuf, HKV_);

    // attention: output written in-place over qbuf (layout (b,t,h,d))
    attn_kernel<<<dim3(B_ * H_ * (T_ / QT)), blk, 0, stream>>>(
        qbuf, kbuf, vbuf, amask, causal, qbuf);

    // output projection
    sgemm_kernel<<<dim3(D_ / BN, BT_ / BM), blk, 0, stream>>>(qbuf, wo, out, BT_, D_, D_);
}

// Round 2
// 674.998 us; speedup vs baseline: 4.6126x; 4.6126x over previous
//
#include <hip/hip_runtime.h>
#include <hip/hip_bf16.h>
#include <stdint.h>

// Problem constants: B=2, T=2048, D=2048, H=16, HKV=4, HD=128
#define B_    2
#define T_    2048
#define D_    2048
#define H_    16
#define HKV_  4
#define HD_   128
#define BT_   (B_ * T_)            // 4096
#define QD_   2048                 // H*HD
#define KVD_  512                  // HKV*HD

typedef float  f32x4 __attribute__((ext_vector_type(4)));
typedef short  s16x8 __attribute__((ext_vector_type(8)));   // 8 bf16 (4 VGPRs) MFMA operand

__device__ __forceinline__ unsigned short f2bf(float f) {
    unsigned int u = __builtin_bit_cast(unsigned int, f);
    u += 0x7FFFu + ((u >> 16) & 1u);              // RNE (finite values only)
    return (unsigned short)(u >> 16);
}
__device__ __forceinline__ float bf2f(unsigned short s) {
    unsigned int u = ((unsigned int)s) << 16;
    return __builtin_bit_cast(float, u);
}

#define GLOBAL_AS __attribute__((address_space(1)))
#define LDS_AS    __attribute__((address_space(3)))

// async global->LDS, 16B per lane. LDS dest = wave-uniform base + lane*16.
__device__ __forceinline__ void gload16(const void* g, void* l) {
    __builtin_amdgcn_global_load_lds((const GLOBAL_AS uint32_t*)g,
                                     (LDS_AS uint32_t*)l, 16, 0, 0);
}

// ---------------------------------------------------------------------------
// Weight transpose+convert: w fp32 [K][N] -> wt bf16 [N][K]
// ---------------------------------------------------------------------------
__global__ __launch_bounds__(256)
void wtrans(const float* __restrict__ w, unsigned short* __restrict__ wt,
            int K, int N) {
    __shared__ float t[32][33];
    const int k0 = blockIdx.x * 32, n0 = blockIdx.y * 32;
    const int tid = threadIdx.x;
    const int r = tid >> 3, c4 = (tid & 7) << 2;
    const float4 v = *(const float4*)&w[(size_t)(k0 + r) * N + n0 + c4];
    t[r][c4 + 0] = v.x; t[r][c4 + 1] = v.y; t[r][c4 + 2] = v.z; t[r][c4 + 3] = v.w;
    __syncthreads();
    ushort4 o;
    o.x = f2bf(t[c4 + 0][r]); o.y = f2bf(t[c4 + 1][r]);
    o.z = f2bf(t[c4 + 2][r]); o.w = f2bf(t[c4 + 3][r]);
    *(ushort4*)&wt[(size_t)(n0 + r) * K + k0 + c4] = o;
}

// ---------------------------------------------------------------------------
// bf16 MFMA GEMM: C[M][N] = A[M][K] * Bt[N][K]^T   (both operands bf16 in LDS)
// 128x128 tile, BK=32, 256 threads (4 waves, 2x2, each 64x64 = 4x4 frags).
// AF32: A source is fp32, reg-staged with conversion. Else bf16 global_load_lds.
// OUTMODE: 0 = bf16 row-major, 1 = f32 row-major,
//          2 = fused KV (N=1024): cols 0..511 -> kb[BT][512] bf16,
//              cols 512..1023 -> vt[(b*HKV+kv)*128+d][T] bf16 (V transposed)
// ---------------------------------------------------------------------------
template <bool AF32, int OUTMODE>
__global__ __launch_bounds__(256)
void gemm_bf16(const void* __restrict__ Ap, const unsigned short* __restrict__ Bt,
               void* __restrict__ Cp, int M, int N, int K) {
    __shared__ unsigned short As[128 * 32];
    __shared__ unsigned short Bs[128 * 32];

    const int tid  = threadIdx.x;
    const int lane = tid & 63;
    const int w    = tid >> 6;
    const int lrow = lane & 15;
    const int lhi  = lane >> 4;
    const int wm   = w >> 1;
    const int wn   = w & 1;
    const int mbase = blockIdx.y * 128;
    const int nbase = blockIdx.x * 128;

    f32x4 acc[4][4] = {};

    for (int k0 = 0; k0 < K; k0 += 32) {
        __syncthreads();
        // ---- stage A tile [128 m][32 k], chunk = 8 bf16, swizzle c^=(row&3) ----
        if constexpr (AF32) {
            const float* A = (const float*)Ap;
#pragma unroll
            for (int i = 0; i < 2; ++i) {
                const int c   = tid * 2 + i;          // 0..511
                const int row = c >> 2, cc = c & 3;
                const float* src = A + (size_t)(mbase + row) * K + k0 + ((cc ^ (row & 3)) << 3);
                const float4 v0 = *(const float4*)src;
                const float4 v1 = *(const float4*)(src + 4);
                s16x8 o;
                o[0] = (short)f2bf(v0.x); o[1] = (short)f2bf(v0.y);
                o[2] = (short)f2bf(v0.z); o[3] = (short)f2bf(v0.w);
                o[4] = (short)f2bf(v1.x); o[5] = (short)f2bf(v1.y);
                o[6] = (short)f2bf(v1.z); o[7] = (short)f2bf(v1.w);
                *(s16x8*)&As[c * 8] = o;
            }
        } else {
            const unsigned short* A = (const unsigned short*)Ap;
#pragma unroll
            for (int i = 0; i < 2; ++i) {
                const int cb = i * 256 + w * 64;      // wave-uniform chunk base
                const int c  = cb + lane;
                const int row = c >> 2, cc = c & 3;
                gload16(A + (size_t)(mbase + row) * K + k0 + ((cc ^ (row & 3)) << 3),
                        &As[cb * 8]);
            }
        }
        // ---- stage B tile [128 n][32 k] ----
#pragma unroll
        for (int i = 0; i < 2; ++i) {
            const int cb = i * 256 + w * 64;
            const int c  = cb + lane;
            const int row = c >> 2, cc = c & 3;
            gload16(Bt + (size_t)(nbase + row) * K + k0 + ((cc ^ (row & 3)) << 3),
                    &Bs[cb * 8]);
        }
        __syncthreads();

        s16x8 af[4], bfv[4];
#pragma unroll
        for (int mi = 0; mi < 4; ++mi) {
            const int r = wm * 64 + mi * 16 + lrow;
            af[mi] = *(const s16x8*)&As[r * 32 + ((lhi ^ (r & 3)) << 3)];
        }
#pragma unroll
        for (int ni = 0; ni < 4; ++ni) {
            const int r = wn * 64 + ni * 16 + lrow;
            bfv[ni] = *(const s16x8*)&Bs[r * 32 + ((lhi ^ (r & 3)) << 3)];
        }
#pragma unroll
        for (int mi = 0; mi < 4; ++mi)
#pragma unroll
            for (int ni = 0; ni < 4; ++ni)
                acc[mi][ni] = __builtin_amdgcn_mfma_f32_16x16x32_bf16(
                    af[mi], bfv[ni], acc[mi][ni], 0, 0, 0);
    }

    // epilogue: D col = lane&15, row = (lane>>4)*4 + reg  [HW-verified layout]
#pragma unroll
    for (int mi = 0; mi < 4; ++mi) {
#pragma unroll
        for (int ni = 0; ni < 4; ++ni) {
#pragma unroll
            for (int r = 0; r < 4; ++r) {
                const int gm = mbase + wm * 64 + mi * 16 + lhi * 4 + r;
                const int gn = nbase + wn * 64 + ni * 16 + lrow;
                const float v = acc[mi][ni][r];
                if constexpr (OUTMODE == 0) {
                    ((unsigned short*)Cp)[(size_t)gm * N + gn] = f2bf(v);
                } else if constexpr (OUTMODE == 1) {
                    ((float*)Cp)[(size_t)gm * N + gn] = v;
                } else {
                    const int b = gm >> 11, t = gm & (T_ - 1);
                    if (gn < KVD_) {
                        ((unsigned short*)Cp)[(size_t)gm * KVD_ + gn] = f2bf(v);
                    } else {
                        const int nv = gn - KVD_;
                        unsigned short* vt = (unsigned short*)Cp + (size_t)BT_ * KVD_;
                        vt[((size_t)(b * HKV_ + (nv >> 7)) * 128 + (nv & 127)) * T_ + t] = f2bf(v);
                    }
                }
            }
        }
    }
}

// ---------------------------------------------------------------------------
// RoPE in-place on bf16 buffer [BT][NH*128]; pair (i, i+64) per head.
// ---------------------------------------------------------------------------
__global__ void rope_bf16(unsigned short* __restrict__ x, int NH, int total) {
    const float nl = -0.14391156642478335f;   // -ln(10000)/64
    for (int idx = blockIdx.x * blockDim.x + threadIdx.x; idx < total;
         idx += gridDim.x * blockDim.x) {
        const int i   = idx & 63;
        const int h   = (idx >> 6) % NH;
        const int row = idx / (NH * 64);
        const int t   = row & (T_ - 1);
        const float ang = (float)t * __expf((float)i * nl);
        float s, c;
        sincosf(ang, &s, &c);
        const size_t base = (size_t)row * (NH * 128) + h * 128 + i;
        const float x1 = bf2f(x[base]);
        const float x2 = bf2f(x[base + 64]);
        x[base]      = f2bf(x1 * c - x2 * s);
        x[base + 64] = f2bf(x2 * c + x1 * s);
    }
}

// ---------------------------------------------------------------------------
// MFMA flash attention (bf16 inputs, fp32 online softmax).
// Block = (q-tile 64, h, b), 256 threads = 4 waves x 16 q-rows.
// K staged via swizzled global_load_lds; V read from pre-transposed global vt
// into 80B-padded LDS rows (conflict-free frag reads); P via per-wave LDS.
// Output bf16 written in-place over the Q buffer ((b,t,h,d) layout).
// ---------------------------------------------------------------------------
__global__ __launch_bounds__(256)
void attn_mfma(const unsigned short* __restrict__ qg,
               const unsigned short* __restrict__ kg,
               const unsigned short* __restrict__ vtg,
               const int* __restrict__ amask,
               const int* __restrict__ causal_p,
               unsigned short* __restrict__ outg) {
    __shared__ unsigned short Qs[64 * 128];    // 16 KB, chunk-swizzled
    __shared__ unsigned short Ks[32 * 128];    // 8 KB, chunk-swizzled
    __shared__ unsigned short Vt[128 * 40];    // 10 KB, rows padded to 80B
    __shared__ unsigned short Pl[4][16 * 40];  // per-wave P, padded rows

    const int q0 = blockIdx.x * 64;
    const int h  = blockIdx.y;
    const int b  = blockIdx.z;
    const int kv = h >> 2;                     // G = 4
    const int causal = *causal_p;
    const int tid  = threadIdx.x;
    const int lane = tid & 63;
    const int w    = tid >> 6;
    const int lrow = lane & 15, lhi = lane >> 4;

    // stage Q tile [64][128] once (source pre-swizzled: chunk c holds global c^(row&7))
#pragma unroll
    for (int i = 0; i < 4; ++i) {
        const int cb = i * 256 + w * 64;
        const int c  = cb + lane;
        const int row = c >> 4, cc = c & 15;
        gload16(qg + (size_t)(b * T_ + q0 + row) * QD_ + h * HD_ + ((cc ^ (row & 7)) << 3),
                &Qs[cb * 8]);
    }
    __syncthreads();

    // hoist Q fragments: wave w owns q-rows w*16 .. w*16+15
    s16x8 qf[4];
#pragma unroll
    for (int kc = 0; kc < 4; ++kc) {
        const int r = w * 16 + lrow;
        qf[kc] = *(const s16x8*)&Qs[r * 128 + (((kc * 4 + lhi) ^ (r & 7)) << 3)];
    }

    f32x4 o[8] = {};
    float m_run[4] = {-__builtin_inff(), -__builtin_inff(),
                      -__builtin_inff(), -__builtin_inff()};
    float l_run[4] = {0.f, 0.f, 0.f, 0.f};

    const int qpos_base = q0 + w * 16 + lhi * 4;   // + r
    const int smax = causal ? (q0 + 64) : T_;
    const float rscale = 0.08838834764831845f;     // 1/sqrt(128)

    for (int s0 = 0; s0 < smax; s0 += 32) {
        __syncthreads();
        // stage K tile [32][128] via gload_lds (swizzled source)
#pragma unroll
        for (int i = 0; i < 2; ++i) {
            const int cb = i * 256 + w * 64;
            const int c  = cb + lane;
            const int row = c >> 4, cc = c & 15;
            gload16(kg + (size_t)(b * T_ + s0 + row) * KVD_ + kv * HD_ + ((cc ^ (row & 7)) << 3),
                    &Ks[cb * 8]);
        }
        // stage Vt tile [128 d][32 s] reg-staged into padded rows
#pragma unroll
        for (int i = 0; i < 2; ++i) {
            const int c = tid * 2 + i;             // 0..511
            const int row = c >> 2, cc = c & 3;    // row = d
            const s16x8 vv = *(const s16x8*)(vtg +
                (size_t)((b * HKV_ + kv) * 128 + row) * T_ + s0 + cc * 8);
            *(s16x8*)&Vt[row * 40 + cc * 8] = vv;
        }
        __syncthreads();

        // ---- QK^T: S[16 q][32 s] as 2 D-frags ----
        f32x4 sf[2] = {};
#pragma unroll
        for (int ssub = 0; ssub < 2; ++ssub) {
            const int r = ssub * 16 + lrow;
#pragma unroll
            for (int kc = 0; kc < 4; ++kc) {
                const s16x8 kf = *(const s16x8*)&Ks[r * 128 + (((kc * 4 + lhi) ^ (r & 7)) << 3)];
                sf[ssub] = __builtin_amdgcn_mfma_f32_16x16x32_bf16(qf[kc], kf, sf[ssub], 0, 0, 0);
            }
        }

        const int sp0 = s0 + lrow, sp1 = s0 + 16 + lrow;
        const int am0 = amask[b * T_ + sp0];
        const int am1 = amask[b * T_ + sp1];

        float p0[4], p1[4], corr[4];
#pragma unroll
        for (int r = 0; r < 4; ++r) {
            const int qp = qpos_base + r;
            float x0 = sf[0][r] * rscale;
            float x1 = sf[1][r] * rscale;
            if ((causal && sp0 > qp) || am0 == 0) x0 = -__builtin_inff();
            if ((causal && sp1 > qp) || am1 == 0) x1 = -__builtin_inff();
            float tmax = fmaxf(x0, x1);
            tmax = fmaxf(tmax, __shfl_xor(tmax, 1));
            tmax = fmaxf(tmax, __shfl_xor(tmax, 2));
            tmax = fmaxf(tmax, __shfl_xor(tmax, 4));
            tmax = fmaxf(tmax, __shfl_xor(tmax, 8));
            const float mn = fmaxf(m_run[r], tmax);
            float cr, e0, e1;
            if (mn == -__builtin_inff()) { cr = 1.f; e0 = 0.f; e1 = 0.f; }
            else {
                cr = __expf(m_run[r] - mn);   // exp(-inf)=0 on first tile
                e0 = __expf(x0 - mn);
                e1 = __expf(x1 - mn);
            }
            float ls = e0 + e1;
            ls += __shfl_xor(ls, 1); ls += __shfl_xor(ls, 2);
            ls += __shfl_xor(ls, 4); ls += __shfl_xor(ls, 8);
            l_run[r] = l_run[r] * cr + ls;
            m_run[r] = mn;
            corr[r] = cr; p0[r] = e0; p1[r] = e1;
        }

        // write P (bf16) to per-wave LDS: Pl[q][s], rows padded to 40
#pragma unroll
        for (int r = 0; r < 4; ++r) {
            Pl[w][(lhi * 4 + r) * 40 + lrow]      = f2bf(p0[r]);
            Pl[w][(lhi * 4 + r) * 40 + 16 + lrow] = f2bf(p1[r]);
        }
        // rescale O accumulators
#pragma unroll
        for (int dc = 0; dc < 8; ++dc)
#pragma unroll
            for (int r = 0; r < 4; ++r) o[dc][r] *= corr[r];

        // ---- PV: O[16 q][128 d] += P[16][32] * V[32][128] ----
        const s16x8 pa = *(const s16x8*)&Pl[w][lrow * 40 + lhi * 8];
#pragma unroll
        for (int dc = 0; dc < 8; ++dc) {
            const s16x8 vb = *(const s16x8*)&Vt[(dc * 16 + lrow) * 40 + lhi * 8];
            o[dc] = __builtin_amdgcn_mfma_f32_16x16x32_bf16(pa, vb, o[dc], 0, 0, 0);
        }
    }

    // normalize + write out (bf16, (b,t,h,d); in-place over Q is safe:
    // each block writes only its own (rows x head-cols) region)
#pragma unroll
    for (int r = 0; r < 4; ++r) {
        const float invl = l_run[r] > 0.f ? 1.0f / l_run[r] : 0.f;
        const int qp = qpos_base + r;
        const size_t base = (size_t)(b * T_ + qp) * QD_ + h * HD_ + lrow;
#pragma unroll
        for (int dc = 0; dc < 8; ++dc)
            outg[base + dc * 16] = f2bf(o[dc][r] * invl);
    }
}

// ---------------------------------------------------------------------------
// kernel_launch
// d_in: 0=x f32[B,T,D], 1=attention_mask i32[B,T], 2=causal i32[1],
//       3=wq f32[D,2048], 4=wk f32[D,512], 5=wv f32[D,512], 6=wo f32[D,D]
// workspace (ushort): wqt[2048*2048] wkvt[1024*2048] wot[2048*2048]
//                     qb[BT*2048] kb[BT*512] vt[BT*512]   (= 46.1 MB)
// ---------------------------------------------------------------------------
extern "C" void kernel_launch(void* const* d_in, const int* in_sizes, int n_in,
                              void* d_out, int out_size, void* d_ws, size_t ws_size,
                              hipStream_t stream) {
    const float* x      = (const float*)d_in[0];
    const int*   amask  = (const int*)d_in[1];
    const int*   causal = (const int*)d_in[2];
    const float* wq     = (const float*)d_in[3];
    const float* wk     = (const float*)d_in[4];
    const float* wv     = (const float*)d_in[5];
    const float* wo     = (const float*)d_in[6];
    float* out = (float*)d_out;

    unsigned short* p    = (unsigned short*)d_ws;
    unsigned short* wqt  = p;  p += (size_t)QD_ * D_;     // [2048][2048]
    unsigned short* wkvt = p;  p += (size_t)1024 * D_;    // [1024][2048] (wk; wv)
    unsigned short* wot  = p;  p += (size_t)D_ * D_;      // [2048][2048]
    unsigned short* qb   = p;  p += (size_t)BT_ * QD_;    // [BT][2048]
    unsigned short* kb   = p;  p += (size_t)BT_ * KVD_;   // [BT][512]
    unsigned short* vt   = p;                              // [(b,kv,d)=1024][T] — adjacent to kb!

    // weight transpose+convert: w[K][N] -> wt[N][K] bf16
    wtrans<<<dim3(64, 64), 256, 0, stream>>>(wq, wqt, D_, QD_);
    wtrans<<<dim3(64, 16), 256, 0, stream>>>(wk, wkvt, D_, KVD_);
    wtrans<<<dim3(64, 16), 256, 0, stream>>>(wv, wkvt + (size_t)KVD_ * D_, D_, KVD_);
    wtrans<<<dim3(64, 64), 256, 0, stream>>>(wo, wot, D_, D_);

    // projections (MFMA bf16; A = x fp32 reg-staged)
    gemm_bf16<true, 0><<<dim3(16, 32), 256, 0, stream>>>(x, wqt, qb, BT_, QD_, D_);
    gemm_bf16<true, 2><<<dim3(8, 32), 256, 0, stream>>>(x, wkvt, kb, BT_, 1024, D_);

    // RoPE (in-place, bf16)
    rope_bf16<<<2048, 256, 0, stream>>>(qb, H_, BT_ * H_ * 64);
    rope_bf16<<<512, 256, 0, stream>>>(kb, HKV_, BT_ * HKV_ * 64);

    // attention (writes bf16 (b,t,h,d) in-place over qb)
    attn_mfma<<<dim3(32, 16, 2), 256, 0, stream>>>(qb, kb, vt, amask, causal, qb);

    // output projection (A = qb bf16 via global_load_lds; C fp32)
    gemm_bf16<false, 1><<<dim3(16, 32), 256, 0, stream>>>(qb, wot, out, BT_, QD_, D_);
}

// Round 5
// 458.222 us; speedup vs baseline: 6.7947x; 1.4731x over previous
//
#include <hip/hip_runtime.h>
#include <hip/hip_bf16.h>
#include <stdint.h>

// Problem constants: B=2, T=2048, D=2048, H=16, HKV=4, HD=128
#define B_    2
#define T_    2048
#define D_    2048
#define H_    16
#define HKV_  4
#define HD_   128
#define BT_   (B_ * T_)            // 4096
#define QD_   2048                 // H*HD
#define KVD_  512                  // HKV*HD

typedef float  f32x4 __attribute__((ext_vector_type(4)));
typedef short  s16x8 __attribute__((ext_vector_type(8)));   // 8 bf16 (4 VGPRs) MFMA operand
typedef unsigned short us;

__device__ __forceinline__ us f2bf(float f) {
    unsigned int u = __builtin_bit_cast(unsigned int, f);
    u += 0x7FFFu + ((u >> 16) & 1u);              // RNE (finite values only)
    return (us)(u >> 16);
}
__device__ __forceinline__ float bf2f(us s) {
    unsigned int u = ((unsigned int)s) << 16;
    return __builtin_bit_cast(float, u);
}
__device__ __forceinline__ unsigned pack2(float a, float b) {
    return (unsigned)f2bf(a) | ((unsigned)f2bf(b) << 16);
}

#define GLOBAL_AS __attribute__((address_space(1)))
#define LDS_AS    __attribute__((address_space(3)))

// async global->LDS, 16B per lane. LDS dest = wave-uniform base + lane*16.
__device__ __forceinline__ void gload16(const void* g, void* l) {
    __builtin_amdgcn_global_load_lds((const GLOBAL_AS uint32_t*)g,
                                     (LDS_AS uint32_t*)l, 16, 0, 0);
}

// ---------------------------------------------------------------------------
// Weight transpose+convert: w fp32 [K][N] -> wt bf16 [N][K]
// ---------------------------------------------------------------------------
__global__ __launch_bounds__(256)
void wtrans(const float* __restrict__ w, us* __restrict__ wt, int K, int N) {
    __shared__ float t[32][33];
    const int k0 = blockIdx.x * 32, n0 = blockIdx.y * 32;
    const int tid = threadIdx.x;
    const int r = tid >> 3, c4 = (tid & 7) << 2;
    const float4 v = *(const float4*)&w[(size_t)(k0 + r) * N + n0 + c4];
    t[r][c4 + 0] = v.x; t[r][c4 + 1] = v.y; t[r][c4 + 2] = v.z; t[r][c4 + 3] = v.w;
    __syncthreads();
    ushort4 o;
    o.x = f2bf(t[c4 + 0][r]); o.y = f2bf(t[c4 + 1][r]);
    o.z = f2bf(t[c4 + 2][r]); o.w = f2bf(t[c4 + 3][r]);
    *(ushort4*)&wt[(size_t)(n0 + r) * K + k0 + c4] = o;
}

// ---------------------------------------------------------------------------
// x fp32 -> bf16 (8 elems/thread)
// ---------------------------------------------------------------------------
__global__ __launch_bounds__(256)
void cvt_bf16(const float* __restrict__ x, us* __restrict__ xb, int n8) {
    const int i = blockIdx.x * 256 + threadIdx.x;
    if (i >= n8) return;
    const float4 a = ((const float4*)x)[i * 2];
    const float4 b = ((const float4*)x)[i * 2 + 1];
    s16x8 o;
    o[0] = (short)f2bf(a.x); o[1] = (short)f2bf(a.y);
    o[2] = (short)f2bf(a.z); o[3] = (short)f2bf(a.w);
    o[4] = (short)f2bf(b.x); o[5] = (short)f2bf(b.y);
    o[6] = (short)f2bf(b.z); o[7] = (short)f2bf(b.w);
    *(s16x8*)&xb[(size_t)i * 8] = o;
}

// ---------------------------------------------------------------------------
// RoPE cos/sin table [t][0..63]=cos, [t][64..127]=sin; bias from attention_mask
// ---------------------------------------------------------------------------
__global__ __launch_bounds__(256)
void build_tabs(float* __restrict__ tab, float* __restrict__ bias,
                const int* __restrict__ amask) {
    const int i = blockIdx.x * 256 + threadIdx.x;
    if (i < T_ * 64) {
        const int t = i >> 6, f = i & 63;
        const float inv = __expf((float)f * (-0.14391156642478335f)); // -ln(1e4)/64
        float s, c;
        sincosf((float)t * inv, &s, &c);
        tab[t * 128 + f] = c;
        tab[t * 128 + 64 + f] = s;
    }
    if (i < B_ * T_) bias[i] = amask[i] ? 0.f : -__builtin_inff();
}

// ---------------------------------------------------------------------------
// RoPE apply (in-place, bf16), table-based, 4 freqs/thread.
// ---------------------------------------------------------------------------
template <int NH>
__global__ __launch_bounds__(256)
void rope_apply(us* __restrict__ x, const float* __restrict__ tab, int total4) {
    const int idx = blockIdx.x * 256 + threadIdx.x;
    if (idx >= total4) return;
    const int i0  = (idx & 15) << 2;
    const int rest = idx >> 4;
    const int h   = rest % NH;
    const int row = rest / NH;
    const int t   = row & (T_ - 1);
    const f32x4 c = *(const f32x4*)&tab[t * 128 + i0];
    const f32x4 s = *(const f32x4*)&tab[t * 128 + 64 + i0];
    const size_t base = (size_t)row * (NH * 128) + h * 128 + i0;
    ushort4 lo = *(ushort4*)&x[base];
    ushort4 hi = *(ushort4*)&x[base + 64];
    float x1[4] = {bf2f(lo.x), bf2f(lo.y), bf2f(lo.z), bf2f(lo.w)};
    float x2[4] = {bf2f(hi.x), bf2f(hi.y), bf2f(hi.z), bf2f(hi.w)};
    ushort4 olo, ohi;
    olo.x = f2bf(x1[0]*c[0] - x2[0]*s[0]); ohi.x = f2bf(x2[0]*c[0] + x1[0]*s[0]);
    olo.y = f2bf(x1[1]*c[1] - x2[1]*s[1]); ohi.y = f2bf(x2[1]*c[1] + x1[1]*s[1]);
    olo.z = f2bf(x1[2]*c[2] - x2[2]*s[2]); ohi.z = f2bf(x2[2]*c[2] + x1[2]*s[2]);
    olo.w = f2bf(x1[3]*c[3] - x2[3]*s[3]); ohi.w = f2bf(x2[3]*c[3] + x1[3]*s[3]);
    *(ushort4*)&x[base]      = olo;
    *(ushort4*)&x[base + 64] = ohi;
}

// ---------------------------------------------------------------------------
// bf16 MFMA GEMM: C[M][N] = A[M][K] * Bt[N][K]^T
// 128x128 tile, BK=32, 256 threads (4 waves, 2x2, each 64x64 = 4x4 frags).
// AF32: A source fp32, reg-staged+converted. Else bf16 via global_load_lds.
// OUTMODE: 0 = bf16 row-major, 1 = f32 row-major,
//          2 = fused KV (N=1024): cols 0..511 -> kb[BT][512] bf16,
//              cols 512..1023 -> vt[(b*HKV+kv)*128+d][T] bf16 (V transposed)
// ---------------------------------------------------------------------------
template <bool AF32, int OUTMODE>
__global__ __launch_bounds__(256)
void gemm_bf16(const void* __restrict__ Ap, const us* __restrict__ Bt,
               void* __restrict__ Cp, int M, int N, int K) {
    __shared__ us As[128 * 32];
    __shared__ us Bs[128 * 32];

    const int tid  = threadIdx.x;
    const int lane = tid & 63;
    const int w    = tid >> 6;
    const int lrow = lane & 15;
    const int lhi  = lane >> 4;
    const int wm   = w >> 1;
    const int wn   = w & 1;
    const int mbase = blockIdx.y * 128;
    const int nbase = blockIdx.x * 128;

    f32x4 acc[4][4] = {};

    for (int k0 = 0; k0 < K; k0 += 32) {
        __syncthreads();
        if constexpr (AF32) {
            const float* A = (const float*)Ap;
#pragma unroll
            for (int i = 0; i < 2; ++i) {
                const int c   = tid * 2 + i;
                const int row = c >> 2, cc = c & 3;
                const float* src = A + (size_t)(mbase + row) * K + k0 + ((cc ^ (row & 3)) << 3);
                const float4 v0 = *(const float4*)src;
                const float4 v1 = *(const float4*)(src + 4);
                s16x8 o;
                o[0] = (short)f2bf(v0.x); o[1] = (short)f2bf(v0.y);
                o[2] = (short)f2bf(v0.z); o[3] = (short)f2bf(v0.w);
                o[4] = (short)f2bf(v1.x); o[5] = (short)f2bf(v1.y);
                o[6] = (short)f2bf(v1.z); o[7] = (short)f2bf(v1.w);
                *(s16x8*)&As[c * 8] = o;
            }
        } else {
            const us* A = (const us*)Ap;
#pragma unroll
            for (int i = 0; i < 2; ++i) {
                const int cb = i * 256 + w * 64;
                const int c  = cb + lane;
                const int row = c >> 2, cc = c & 3;
                gload16(A + (size_t)(mbase + row) * K + k0 + ((cc ^ (row & 3)) << 3),
                        &As[cb * 8]);
            }
        }
#pragma unroll
        for (int i = 0; i < 2; ++i) {
            const int cb = i * 256 + w * 64;
            const int c  = cb + lane;
            const int row = c >> 2, cc = c & 3;
            gload16(Bt + (size_t)(nbase + row) * K + k0 + ((cc ^ (row & 3)) << 3),
                    &Bs[cb * 8]);
        }
        __syncthreads();

        s16x8 af[4], bfv[4];
#pragma unroll
        for (int mi = 0; mi < 4; ++mi) {
            const int r = wm * 64 + mi * 16 + lrow;
            af[mi] = *(const s16x8*)&As[r * 32 + ((lhi ^ (r & 3)) << 3)];
        }
#pragma unroll
        for (int ni = 0; ni < 4; ++ni) {
            const int r = wn * 64 + ni * 16 + lrow;
            bfv[ni] = *(const s16x8*)&Bs[r * 32 + ((lhi ^ (r & 3)) << 3)];
        }
#pragma unroll
        for (int mi = 0; mi < 4; ++mi)
#pragma unroll
            for (int ni = 0; ni < 4; ++ni)
                acc[mi][ni] = __builtin_amdgcn_mfma_f32_16x16x32_bf16(
                    af[mi], bfv[ni], acc[mi][ni], 0, 0, 0);
    }

    // epilogue: D col = lane&15, row = (lane>>4)*4 + reg  [HW-verified]
#pragma unroll
    for (int mi = 0; mi < 4; ++mi) {
#pragma unroll
        for (int ni = 0; ni < 4; ++ni) {
#pragma unroll
            for (int r = 0; r < 4; ++r) {
                const int gm = mbase + wm * 64 + mi * 16 + lhi * 4 + r;
                const int gn = nbase + wn * 64 + ni * 16 + lrow;
                const float v = acc[mi][ni][r];
                if constexpr (OUTMODE == 0) {
                    ((us*)Cp)[(size_t)gm * N + gn] = f2bf(v);
                } else if constexpr (OUTMODE == 1) {
                    ((float*)Cp)[(size_t)gm * N + gn] = v;
                } else {
                    const int b = gm >> 11, t = gm & (T_ - 1);
                    if (gn < KVD_) {
                        ((us*)Cp)[(size_t)gm * KVD_ + gn] = f2bf(v);
                    } else {
                        const int nv = gn - KVD_;
                        us* vt = (us*)Cp + (size_t)BT_ * KVD_;
                        vt[((size_t)(b * HKV_ + (nv >> 7)) * 128 + (nv & 127)) * T_ + t] = f2bf(v);
                    }
                }
            }
        }
    }
}

// ---------------------------------------------------------------------------
// MFMA flash attention, swapped-QK^T, in-register softmax.
// Block = (q-tile 64, h, b), 4 waves x 16 q-rows. KVBLK = 64.
// K,V double-buffered LDS via global_load_lds (XOR chunk swizzle both sides).
// Q staged once into K-buffer-1 region, hoisted to regs. 64 KB LDS total.
// ---------------------------------------------------------------------------
__global__ __launch_bounds__(256)
void attn_mfma2(const us* __restrict__ qg, const us* __restrict__ kg,
                const us* __restrict__ vtg, const float* __restrict__ bias,
                const int* __restrict__ causal_p, us* __restrict__ outg) {
    __shared__ us lds[32768];   // K:[2][64*128] @0, V^T:[2][128*64] @16384

    const int q0 = blockIdx.x * 64;
    const int h  = blockIdx.y;
    const int b  = blockIdx.z;
    const int kvh = h >> 2;
    const int causal = *causal_p;
    const int tid  = threadIdx.x;
    const int lane = tid & 63;
    const int w    = tid >> 6;
    const int lrow = lane & 15, lhi = lane >> 4;

    auto stageKV = [&](int buf, int s0) {
        us* Kd = lds + buf * 8192;
        us* Vd = lds + 16384 + buf * 8192;
#pragma unroll
        for (int i = 0; i < 4; ++i) {          // K [64 kv][128 d], 16 chunks/row
            const int cb = i * 256 + w * 64;
            const int c  = cb + lane;
            const int row = c >> 4, cc = c & 15;
            gload16(kg + (size_t)(b * T_ + s0 + row) * KVD_ + kvh * HD_ + ((cc ^ (row & 7)) << 3),
                    Kd + cb * 8);
        }
#pragma unroll
        for (int i = 0; i < 4; ++i) {          // V^T [128 d][64 kv], 8 chunks/row
            const int cb = i * 256 + w * 64;
            const int c  = cb + lane;
            const int row = c >> 3, cc = c & 7;
            gload16(vtg + (size_t)((b * HKV_ + kvh) * 128 + row) * T_ + s0 + ((cc ^ (row & 7)) << 3),
                    Vd + cb * 8);
        }
    };

    // ---- stage Q into K-buf-1 region ----
#pragma unroll
    for (int i = 0; i < 4; ++i) {
        const int cb = i * 256 + w * 64;
        const int c  = cb + lane;
        const int row = c >> 4, cc = c & 15;
        gload16(qg + (size_t)(b * T_ + q0 + row) * QD_ + h * HD_ + ((cc ^ (row & 7)) << 3),
                lds + 8192 + cb * 8);
    }
    __syncthreads();

    // hoist Q fragments (wave w owns q-rows w*16 .. w*16+15)
    s16x8 qf[4];
    {
        const us* Qsp = lds + 8192;
        const int qr = w * 16 + lrow;
#pragma unroll
        for (int kc = 0; kc < 4; ++kc)
            qf[kc] = *(const s16x8*)&Qsp[qr * 128 + (((kc * 4 + lhi) ^ (qr & 7)) << 3)];
    }
    stageKV(0, 0);
    __syncthreads();   // qf reads drained; buf0 ready

    f32x4 o[8] = {};
    float m_run = -__builtin_inff();
    float l_run = 0.f;
    const int qp = q0 + w * 16 + lrow;     // softmax lane's q
    const int smax = causal ? (q0 + 64) : T_;
    const int ntiles = smax >> 6;
    const float rscale = 0.08838834764831845f;   // 1/sqrt(128)
    int cur = 0;

    for (int it = 0; it < ntiles; ++it) {
        const int s0 = it << 6;
        if (it + 1 < ntiles) stageKV(cur ^ 1, s0 + 64);

        const us* Kcur = lds + cur * 8192;
        const us* Vcur = lds + 16384 + cur * 8192;

        // ---- QK^T swapped: sf[j] = S^T[kv=j*16+lhi*4+r][q=w*16+lrow] ----
        f32x4 sf[4];
#pragma unroll
        for (int j = 0; j < 4; ++j) {
            f32x4 s = {0.f, 0.f, 0.f, 0.f};
            const int kr = j * 16 + lrow;
#pragma unroll
            for (int kc = 0; kc < 4; ++kc) {
                const s16x8 kf = *(const s16x8*)&Kcur[kr * 128 + (((kc * 4 + lhi) ^ (kr & 7)) << 3)];
                s = __builtin_amdgcn_mfma_f32_16x16x32_bf16(kf, qf[kc], s, 0, 0, 0);
            }
            sf[j] = s;
        }

        // ---- scale + bias + causal mask (all lane-local) ----
        const float* brow = bias + b * T_ + s0;
        f32x4 bv[4];
#pragma unroll
        for (int j = 0; j < 4; ++j)
            bv[j] = *(const f32x4*)&brow[j * 16 + lhi * 4];
        const bool needc = causal && (s0 + 63 > q0 + w * 16);
        float x[4][4];
#pragma unroll
        for (int j = 0; j < 4; ++j)
#pragma unroll
            for (int r = 0; r < 4; ++r) {
                float xv = sf[j][r] * rscale + bv[j][r];
                if (needc && (s0 + j * 16 + lhi * 4 + r > qp)) xv = -__builtin_inff();
                x[j][r] = xv;
            }

        // ---- in-register online softmax (16 vals/lane + 2 shfl) ----
        float tmax = x[0][0];
#pragma unroll
        for (int j = 0; j < 4; ++j)
#pragma unroll
            for (int r = 0; r < 4; ++r) tmax = fmaxf(tmax, x[j][r]);
        tmax = fmaxf(tmax, __shfl_xor(tmax, 16));
        tmax = fmaxf(tmax, __shfl_xor(tmax, 32));
        const float mn = fmaxf(m_run, tmax);
        float corr, ls = 0.f, ps[4][4];
        if (mn == -__builtin_inff()) {
            corr = 1.f;
#pragma unroll
            for (int j = 0; j < 4; ++j)
#pragma unroll
                for (int r = 0; r < 4; ++r) ps[j][r] = 0.f;
        } else {
            corr = __expf(m_run - mn);
#pragma unroll
            for (int j = 0; j < 4; ++j)
#pragma unroll
                for (int r = 0; r < 4; ++r) { ps[j][r] = __expf(x[j][r] - mn); ls += ps[j][r]; }
        }
        ls += __shfl_xor(ls, 16);
        ls += __shfl_xor(ls, 32);
        l_run = l_run * corr + ls;
        m_run = mn;

        // ---- build PV A-frags: shuffle BOTH j-candidates, select on the
        //      DESTINATION side (round-3 bug: source-side ?: picked the wrong
        //      16-kv block for dest lanes with lhi>>1 != src lhi>>1) ----
        const unsigned w00 = pack2(ps[0][0], ps[0][1]), w01 = pack2(ps[0][2], ps[0][3]);
        const unsigned w10 = pack2(ps[1][0], ps[1][1]), w11 = pack2(ps[1][2], ps[1][3]);
        const unsigned w20 = pack2(ps[2][0], ps[2][1]), w21 = pack2(ps[2][2], ps[2][3]);
        const unsigned w30 = pack2(ps[3][0], ps[3][1]), w31 = pack2(ps[3][2], ps[3][3]);
        int a0w[4], a1w[4];
#pragma unroll
        for (int m = 0; m < 4; ++m) {
            const int src = lrow + ((lhi & 1) << 5) + ((m & 2) << 3);
            const unsigned c0 = (m & 1) ? w01 : w00;   // j=0 word (pair m&1)
            const unsigned c1 = (m & 1) ? w11 : w10;   // j=1 word
            const int t0 = __shfl((int)c0, src);
            const int t1 = __shfl((int)c1, src);
            a0w[m] = (lhi & 2) ? t1 : t0;              // dest-side j select
            const unsigned c2 = (m & 1) ? w21 : w20;   // j=2 word
            const unsigned c3 = (m & 1) ? w31 : w30;   // j=3 word
            const int t2 = __shfl((int)c2, src);
            const int t3 = __shfl((int)c3, src);
            a1w[m] = (lhi & 2) ? t3 : t2;
        }
        const s16x8 a0 = __builtin_bit_cast(s16x8, make_int4(a0w[0], a0w[1], a0w[2], a0w[3]));
        const s16x8 a1 = __builtin_bit_cast(s16x8, make_int4(a1w[0], a1w[1], a1w[2], a1w[3]));

        // ---- rescale O (corr broadcast to O-row owners) + PV ----
        float co[4];
#pragma unroll
        for (int r = 0; r < 4; ++r) co[r] = __shfl(corr, lhi * 4 + r);
#pragma unroll
        for (int dc = 0; dc < 8; ++dc) {
            o[dc][0] *= co[0]; o[dc][1] *= co[1];
            o[dc][2] *= co[2]; o[dc][3] *= co[3];
        }
#pragma unroll
        for (int dc = 0; dc < 8; ++dc) {
            const int vr = dc * 16 + lrow;
            const s16x8 vb0 = *(const s16x8*)&Vcur[vr * 64 + ((lhi ^ (vr & 7)) << 3)];
            o[dc] = __builtin_amdgcn_mfma_f32_16x16x32_bf16(a0, vb0, o[dc], 0, 0, 0);
            const s16x8 vb1 = *(const s16x8*)&Vcur[vr * 64 + (((4 + lhi) ^ (vr & 7)) << 3)];
            o[dc] = __builtin_amdgcn_mfma_f32_16x16x32_bf16(a1, vb1, o[dc], 0, 0, 0);
        }
        __syncthreads();
        cur ^= 1;
    }

    // ---- normalize + write (bf16, (b,t,h,d); in-place over Q is safe) ----
    float lq[4];
#pragma unroll
    for (int r = 0; r < 4; ++r) lq[r] = __shfl(l_run, lhi * 4 + r);
#pragma unroll
    for (int r = 0; r < 4; ++r) {
        const float invl = lq[r] > 0.f ? 1.0f / lq[r] : 0.f;
        const size_t base = (size_t)(b * T_ + q0 + w * 16 + lhi * 4 + r) * QD_ + h * HD_ + lrow;
#pragma unroll
        for (int dc = 0; dc < 8; ++dc)
            outg[base + dc * 16] = f2bf(o[dc][r] * invl);
    }
}

// ---------------------------------------------------------------------------
// kernel_launch
// d_in: 0=x f32[B,T,D], 1=attention_mask i32[B,T], 2=causal i32[1],
//       3=wq f32[D,2048], 4=wk f32[D,512], 5=wv f32[D,512], 6=wo f32[D,D]
// ws (us units): wqt 4.19M | wkvt 2.10M | qb 8.39M | kb 2.10M | vt 2.10M |
//   tab(f32) 0.52M | bias(f32) 8K | xw: xb 8.39M (overlapped by wot) = 55.6MB
//   (fallback without xb: 47.2MB; round-2 proved ws >= 47MB)
// ---------------------------------------------------------------------------
extern "C" void kernel_launch(void* const* d_in, const int* in_sizes, int n_in,
                              void* d_out, int out_size, void* d_ws, size_t ws_size,
                              hipStream_t stream) {
    const float* x      = (const float*)d_in[0];
    const int*   amask  = (const int*)d_in[1];
    const int*   causal = (const int*)d_in[2];
    const float* wq     = (const float*)d_in[3];
    const float* wk     = (const float*)d_in[4];
    const float* wv     = (const float*)d_in[5];
    const float* wo     = (const float*)d_in[6];
    float* out = (float*)d_out;

    us* p    = (us*)d_ws;
    us* wqt  = p;  p += (size_t)QD_ * D_;        // 4,194,304
    us* wkvt = p;  p += (size_t)1024 * D_;       // 2,097,152 (wk; wv)
    us* qb   = p;  p += (size_t)BT_ * QD_;       // 8,388,608
    us* kb   = p;  p += (size_t)BT_ * KVD_;      // 2,097,152
    us* vt   = p;  p += (size_t)BT_ * KVD_;      // 2,097,152 (must follow kb!)
    float* tab  = (float*)p;  p += (size_t)T_ * 128 * 2;   // 524,288 us
    float* bias = (float*)p;  p += (size_t)B_ * T_ * 2;    // 8,192 us
    us* xw   = p;                                 // xb (8.39M us) / wot (4.19M us)

    const size_t need_xb = ((size_t)(p - (us*)d_ws) + (size_t)BT_ * D_) * sizeof(us);
    const bool useXB = ws_size >= need_xb;

    build_tabs<<<512, 256, 0, stream>>>(tab, bias, amask);
    wtrans<<<dim3(64, 64), 256, 0, stream>>>(wq, wqt, D_, QD_);
    wtrans<<<dim3(64, 16), 256, 0, stream>>>(wk, wkvt, D_, KVD_);
    wtrans<<<dim3(64, 16), 256, 0, stream>>>(wv, wkvt + (size_t)KVD_ * D_, D_, KVD_);

    if (useXB) {
        cvt_bf16<<<4096, 256, 0, stream>>>(x, xw, BT_ * D_ / 8);
        gemm_bf16<false, 0><<<dim3(16, 32), 256, 0, stream>>>(xw, wqt, qb, BT_, QD_, D_);
        gemm_bf16<false, 2><<<dim3(8, 32), 256, 0, stream>>>(xw, wkvt, kb, BT_, 1024, D_);
    } else {
        gemm_bf16<true, 0><<<dim3(16, 32), 256, 0, stream>>>(x, wqt, qb, BT_, QD_, D_);
        gemm_bf16<true, 2><<<dim3(8, 32), 256, 0, stream>>>(x, wkvt, kb, BT_, 1024, D_);
    }

    rope_apply<H_><<<4096, 256, 0, stream>>>(qb, tab, BT_ * H_ * 16);
    rope_apply<HKV_><<<1024, 256, 0, stream>>>(kb, tab, BT_ * HKV_ * 16);

    attn_mfma2<<<dim3(32, 16, 2), 256, 0, stream>>>(qb, kb, vt, bias, causal, qb);

    // wo transpose into xw (xb is dead by now if useXB)
    wtrans<<<dim3(64, 64), 256, 0, stream>>>(wo, xw, D_, D_);
    gemm_bf16<false, 1><<<dim3(16, 32), 256, 0, stream>>>(qb, xw, out, BT_, D_, D_);
}